// Round 1
// baseline (111.863 us; speedup 1.0000x reference)
//
#include <hip/hip_runtime.h>

#define B 8
#define CCH 3
#define HH 512
#define WW 512
#define WIN 21
#define PAD 10
#define TS 32           // output tile (x and y)
#define PT (TS + 2*PAD) // 52 padded tile

__global__ __launch_bounds__(256) void nlm_fused_kernel(const float* __restrict__ noisy,
                                                        float* __restrict__ out) {
    __shared__ float tile[PT][PT + 1];   // 52 x 53 floats
    __shared__ float hs1[PT][TS + 1];    // 52 x 33
    __shared__ float hs2[PT][TS + 1];

    const int tid = threadIdx.x;
    const int tx  = tid & 31;
    const int tyb = tid >> 5;        // 0..7
    const int ly0 = tyb * 4;         // this thread's 4 consecutive output rows

    const int x0 = blockIdx.x * TS;
    const int y0 = blockIdx.y * TS;
    const int ch = blockIdx.z;

    float num[4] = {0.f, 0.f, 0.f, 0.f};
    float den[4] = {0.f, 0.f, 0.f, 0.f};

    for (int b = 0; b < B; ++b) {
        const float* src = noisy + (size_t)(b * CCH + ch) * (HH * WW);

        // ---- load reflect-padded 52x52 tile ----
        for (int idx = tid; idx < PT * PT; idx += 256) {
            int r = idx / PT;
            int c = idx - r * PT;
            int gy = y0 + r - PAD;
            gy = (gy < 0) ? -gy : ((gy >= HH) ? (2 * (HH - 1) - gy) : gy);
            int gx = x0 + c - PAD;
            gx = (gx < 0) ? -gx : ((gx >= WW) ? (2 * (WW - 1) - gx) : gx);
            tile[r][c] = src[gy * WW + gx];
        }
        __syncthreads();

        // ---- horizontal box sums (sliding window, 4 cols per work unit) ----
        for (int u = tid; u < PT * 8; u += 256) {
            int r   = u >> 3;
            int cx0 = (u & 7) * 4;
            float s1 = 0.f, s2 = 0.f;
            #pragma unroll
            for (int k = 0; k < WIN; ++k) {
                float v = tile[r][cx0 + k];
                s1 += v;
                s2 += v * v;
            }
            hs1[r][cx0] = s1;
            hs2[r][cx0] = s2;
            #pragma unroll
            for (int j = 1; j < 4; ++j) {
                float vo = tile[r][cx0 + j - 1];
                float vn = tile[r][cx0 + j + WIN - 1];
                s1 += vn - vo;
                s2 += vn * vn - vo * vo;
                hs1[r][cx0 + j] = s1;
                hs2[r][cx0 + j] = s2;
            }
        }
        __syncthreads();

        // ---- vertical sliding box sums + weight accumulate ----
        float vs1 = 0.f, vs2 = 0.f;
        #pragma unroll
        for (int k = 0; k < WIN; ++k) {
            vs1 += hs1[ly0 + k][tx];
            vs2 += hs2[ly0 + k][tx];
        }
        #pragma unroll
        for (int i = 0; i < 4; ++i) {
            if (i > 0) {
                vs1 += hs1[ly0 + i + WIN - 1][tx] - hs1[ly0 + i - 1][tx];
                vs2 += hs2[ly0 + i + WIN - 1][tx] - hs2[ly0 + i - 1][tx];
            }
            float a = tile[ly0 + i + PAD][tx + PAD];  // center pixel noisy[b,c,y,x]
            float p = tile[ly0 + i][tx];              // patch = padded[:, :, :H, :W]
            float d = (vs2 - 2.f * a * vs1 + (float)(WIN * WIN) * a * a)
                      * (1.f / (float)(WIN * WIN));
            float w = __expf(d * -100.0f);            // 1/h^2 = 100
            num[i] += w * p;
            den[i] += w;
        }
        __syncthreads();  // protect tile/hs before next b's load
    }

    // ---- epilogue: identical value for all 8 batch slices ----
    #pragma unroll
    for (int i = 0; i < 4; ++i) {
        int y = y0 + ly0 + i;
        int x = x0 + tx;
        float v = num[i] / (den[i] + 1e-10f);
        v = v < 0.f ? 0.f : (v > 1.f ? 1.f : v);
        #pragma unroll
        for (int b = 0; b < B; ++b) {
            out[((size_t)(b * CCH + ch) * HH + y) * WW + x] = v;
        }
    }
}

extern "C" void kernel_launch(void* const* d_in, const int* in_sizes, int n_in,
                              void* d_out, int out_size, void* d_ws, size_t ws_size,
                              hipStream_t stream) {
    const float* noisy = (const float*)d_in[0];
    float* out = (float*)d_out;
    dim3 grid(WW / TS, HH / TS, CCH);
    nlm_fused_kernel<<<grid, dim3(256), 0, stream>>>(noisy, out);
}

// Round 2
// 109.038 us; speedup vs baseline: 1.0259x; 1.0259x over previous
//
#include <hip/hip_runtime.h>

#define B 8
#define CCH 3
#define HH 512
#define WW 512
#define WIN 21
#define PAD 10
#define TSX 32                 // output tile width
#define TSY 16                 // output tile height
#define PTX (TSX + 2*PAD)      // 52 padded width
#define PTY (TSY + 2*PAD)      // 36 padded height

__global__ __launch_bounds__(256) void nlm_fused_kernel(const float* __restrict__ noisy,
                                                        float* __restrict__ out) {
    __shared__ float  tile[PTY][PTX + 1];   // 36 x 53 floats  (~7.6 KB)
    __shared__ float2 hs[PTY][TSX + 1];     // 36 x 33 float2  (~9.5 KB)  (s1, s2)

    const int tid = threadIdx.x;
    const int tx  = tid & 31;
    const int ty0 = (tid >> 5) * 2;   // 2 consecutive output rows per thread

    const int x0 = blockIdx.x * TSX;
    const int y0 = blockIdx.y * TSY;
    const int ch = blockIdx.z;

    float num[2] = {0.f, 0.f};
    float den[2] = {0.f, 0.f};

    for (int b = 0; b < B; ++b) {
        const float* src = noisy + (size_t)(b * CCH + ch) * (HH * WW);

        // ---- load reflect-padded 36x52 tile ----
        for (int idx = tid; idx < PTY * PTX; idx += 256) {
            int r = idx / PTX;
            int c = idx - r * PTX;
            int gy = y0 + r - PAD;
            gy = (gy < 0) ? -gy : ((gy >= HH) ? (2 * (HH - 1) - gy) : gy);
            int gx = x0 + c - PAD;
            gx = (gx < 0) ? -gx : ((gx >= WW) ? (2 * (WW - 1) - gx) : gx);
            tile[r][c] = src[gy * WW + gx];
        }
        __syncthreads();

        // ---- horizontal box sums: 36 rows x 8 groups of 4 output cols ----
        for (int u = tid; u < PTY * 8; u += 256) {
            int r   = u >> 3;
            int cx0 = (u & 7) * 4;
            float s1 = 0.f, s2 = 0.f;
            #pragma unroll
            for (int k = 0; k < WIN; ++k) {
                float v = tile[r][cx0 + k];
                s1 += v;
                s2 += v * v;
            }
            hs[r][cx0] = make_float2(s1, s2);
            #pragma unroll
            for (int j = 1; j < 4; ++j) {
                float vo = tile[r][cx0 + j - 1];
                float vn = tile[r][cx0 + j + WIN - 1];
                s1 += vn - vo;
                s2 += vn * vn - vo * vo;
                hs[r][cx0 + j] = make_float2(s1, s2);
            }
        }
        __syncthreads();

        // ---- vertical sliding box sums + weight accumulate (2 rows/thread) ----
        float vs1 = 0.f, vs2 = 0.f;
        #pragma unroll
        for (int k = 0; k < WIN; ++k) {
            float2 h = hs[ty0 + k][tx];
            vs1 += h.x;
            vs2 += h.y;
        }
        #pragma unroll
        for (int i = 0; i < 2; ++i) {
            if (i > 0) {
                float2 hn = hs[ty0 + i + WIN - 1][tx];
                float2 ho = hs[ty0 + i - 1][tx];
                vs1 += hn.x - ho.x;
                vs2 += hn.y - ho.y;
            }
            float a = tile[ty0 + i + PAD][tx + PAD];  // center pixel noisy[b,c,y,x]
            float p = tile[ty0 + i][tx];              // patch = padded[:, :, :H, :W]
            float d = (vs2 - 2.f * a * vs1 + (float)(WIN * WIN) * a * a)
                      * (1.f / (float)(WIN * WIN));
            float w = __expf(d * -100.0f);            // 1/h^2 = 100
            num[i] += w * p;
            den[i] += w;
        }
        __syncthreads();  // protect tile/hs before next b's load
    }

    // ---- epilogue: identical value for all 8 batch slices ----
    #pragma unroll
    for (int i = 0; i < 2; ++i) {
        int y = y0 + ty0 + i;
        int x = x0 + tx;
        float v = num[i] / (den[i] + 1e-10f);
        v = v < 0.f ? 0.f : (v > 1.f ? 1.f : v);
        #pragma unroll
        for (int b = 0; b < B; ++b) {
            out[((size_t)(b * CCH + ch) * HH + y) * WW + x] = v;
        }
    }
}

extern "C" void kernel_launch(void* const* d_in, const int* in_sizes, int n_in,
                              void* d_out, int out_size, void* d_ws, size_t ws_size,
                              hipStream_t stream) {
    const float* noisy = (const float*)d_in[0];
    float* out = (float*)d_out;
    dim3 grid(WW / TSX, HH / TSY, CCH);
    nlm_fused_kernel<<<grid, dim3(256), 0, stream>>>(noisy, out);
}

// Round 3
// 103.320 us; speedup vs baseline: 1.0827x; 1.0553x over previous
//
#include <hip/hip_runtime.h>

#define B 8
#define CCH 3
#define HH 512
#define WW 512
#define WIN 21
#define PAD 10
#define TSX 32
#define TSY 16
#define PTX 52                // padded tile width used
#define PTY 36                // padded tile height
#define TROW 56               // tile row stride in floats (16B-aligned rows)
#define HROW 38               // hs_t row stride in float2 (even -> b128-alignable)

__global__ __launch_bounds__(256) void nlm_fused_kernel(const float* __restrict__ noisy,
                                                        float* __restrict__ out) {
    __shared__ float  tile[PTY][TROW];    // 36 x 56 floats  (8064 B)
    __shared__ float2 hs_t[TSX][HROW];    // [col][row] (s1,s2)  (9728 B)

    const int tid = threadIdx.x;
    const int tx  = tid & 31;
    const int ty0 = (tid >> 5) * 2;       // 2 consecutive output rows / thread

    const int x0 = blockIdx.x * TSX;
    const int y0 = blockIdx.y * TSY;
    const int ch = blockIdx.z;

    float num0 = 0.f, num1 = 0.f, den0 = 0.f, den1 = 0.f;

    for (int b = 0; b < B; ++b) {
        const float* src = noisy + (size_t)(b * CCH + ch) * (HH * WW);

        // ---- load reflect-padded 36x52 tile, float4-vectorized ----
        // 36 rows x 13 float4 groups = 468 slots
        for (int s = tid; s < PTY * 13; s += 256) {
            int r  = s / 13;
            int c4 = s - r * 13;
            int gy = y0 + r - PAD;
            gy = (gy < 0) ? -gy : ((gy >= HH) ? (2 * (HH - 1) - gy) : gy);
            int gxs = x0 + (c4 << 2) - PAD;
            float4 v;
            if (gxs >= 0 && gxs <= WW - 4) {
                v = *(const float4*)(src + gy * WW + gxs);     // global_load_dwordx4
            } else {
                float tmp[4];
                #pragma unroll
                for (int t = 0; t < 4; ++t) {
                    int gx = gxs + t;
                    gx = (gx < 0) ? -gx : ((gx >= WW) ? (2 * (WW - 1) - gx) : gx);
                    tmp[t] = src[gy * WW + gx];
                }
                v = make_float4(tmp[0], tmp[1], tmp[2], tmp[3]);
            }
            *(float4*)&tile[r][c4 << 2] = v;                   // ds_write_b128
        }
        __syncthreads();

        // ---- horizontal box sums: 36 rows x 8 groups of 4 output cols ----
        for (int u = tid; u < PTY * 8; u += 256) {
            int r   = u >> 3;
            int cx0 = (u & 7) << 2;
            float v[24];
            #pragma unroll
            for (int q = 0; q < 6; ++q)
                *(float4*)&v[q * 4] = *(const float4*)&tile[r][cx0 + q * 4];  // ds_read_b128
            float s1 = 0.f, s2 = 0.f;
            #pragma unroll
            for (int k = 0; k < WIN; ++k) { s1 += v[k]; s2 += v[k] * v[k]; }
            hs_t[cx0][r] = make_float2(s1, s2);
            #pragma unroll
            for (int j = 1; j < 4; ++j) {
                float vo = v[j - 1], vn = v[j + WIN - 1];
                s1 += vn - vo;
                s2 += vn * vn - vo * vo;
                hs_t[cx0 + j][r] = make_float2(s1, s2);
            }
        }
        __syncthreads();

        // ---- vertical sliding sums: 11 x ds_read_b128 cover rows ty0..ty0+21 ----
        float4 q0 = *(const float4*)&hs_t[tx][ty0];            // rows ty0, ty0+1
        float vs1 = q0.x + q0.z, vs2 = q0.y + q0.w;
        #pragma unroll
        for (int k = 1; k < 10; ++k) {
            float4 q = *(const float4*)&hs_t[tx][ty0 + 2 * k];
            vs1 += q.x + q.z;
            vs2 += q.y + q.w;
        }
        float4 q10 = *(const float4*)&hs_t[tx][ty0 + 20];      // rows ty0+20, ty0+21
        vs1 += q10.x;
        vs2 += q10.y;
        {
            float a = tile[ty0 + PAD][tx + PAD];
            float p = tile[ty0][tx];
            float dd = vs2 - 2.f * a * vs1 + 441.f * a * a;
            float w = __expf(dd * (-100.f / 441.f));
            num0 += w * p;
            den0 += w;
        }
        vs1 += q10.z - q0.x;                                   // slide to row ty0+1
        vs2 += q10.w - q0.y;
        {
            float a = tile[ty0 + 1 + PAD][tx + PAD];
            float p = tile[ty0 + 1][tx];
            float dd = vs2 - 2.f * a * vs1 + 441.f * a * a;
            float w = __expf(dd * (-100.f / 441.f));
            num1 += w * p;
            den1 += w;
        }
        __syncthreads();   // protect tile/hs_t before next batch's load
    }

    // ---- epilogue: identical value for all 8 batch slices ----
    {
        int y = y0 + ty0;
        int x = x0 + tx;
        float v0 = num0 / (den0 + 1e-10f);
        v0 = v0 < 0.f ? 0.f : (v0 > 1.f ? 1.f : v0);
        float v1 = num1 / (den1 + 1e-10f);
        v1 = v1 < 0.f ? 0.f : (v1 > 1.f ? 1.f : v1);
        #pragma unroll
        for (int b = 0; b < B; ++b) {
            size_t base = ((size_t)(b * CCH + ch) * HH + y) * WW + x;
            out[base] = v0;
            out[base + WW] = v1;
        }
    }
}

extern "C" void kernel_launch(void* const* d_in, const int* in_sizes, int n_in,
                              void* d_out, int out_size, void* d_ws, size_t ws_size,
                              hipStream_t stream) {
    const float* noisy = (const float*)d_in[0];
    float* out = (float*)d_out;
    dim3 grid(WW / TSX, HH / TSY, CCH);
    nlm_fused_kernel<<<grid, dim3(256), 0, stream>>>(noisy, out);
}